// Round 2
// baseline (349.141 us; speedup 1.0000x reference)
//
#include <hip/hip_runtime.h>

typedef unsigned short u16;
typedef unsigned int   u32;

#define JX 2048
#define JMM 2048
#define DD 512
#define HHH 512
#define NBATCH 8

typedef short s16x8 __attribute__((ext_vector_type(8)));
typedef float f32x4 __attribute__((ext_vector_type(4)));

static __device__ __forceinline__ u16 f2bf(float f) {
  u32 u = __float_as_uint(f);
  u = (u + 0x7fffu + ((u >> 16) & 1u)) >> 16;
  return (u16)u;
}
static __device__ __forceinline__ float bf2f(u16 h) {
  return __uint_as_float(((u32)h) << 16);
}

static __device__ __forceinline__ f32x4 mfma16(s16x8 a, s16x8 b, f32x4 c) {
  return __builtin_amdgcn_mfma_f32_16x16x32_bf16(a, b, c, 0, 0, 0);
}

// ---------------- flat f32 -> bf16 convert, 8 elems/thread ----------------
__global__ __launch_bounds__(256) void cvt_k(const float* __restrict__ in,
                                             u16* __restrict__ out, int n8) {
  int i = blockIdx.x * 256 + threadIdx.x;
  if (i >= n8) return;
  const float4* p = reinterpret_cast<const float4*>(in);
  float4 a = p[2 * i], b = p[2 * i + 1];
  union { u16 u[8]; uint4 v; } r;
  r.u[0] = f2bf(a.x); r.u[1] = f2bf(a.y); r.u[2] = f2bf(a.z); r.u[3] = f2bf(a.w);
  r.u[4] = f2bf(b.x); r.u[5] = f2bf(b.y); r.u[6] = f2bf(b.z); r.u[7] = f2bf(b.w);
  reinterpret_cast<uint4*>(out)[i] = r.v;
}

// ------------- transpose+convert: in [R,C] f32 -> out [C,R] bf16, batched -------------
__global__ void tcvt_k(const float* __restrict__ in, u16* __restrict__ out,
                       int R, int C, long long ibs, long long obs) {
  __shared__ float t[32][33];
  const float* ip = in + (size_t)blockIdx.z * ibs;
  u16* op = out + (size_t)blockIdx.z * obs;
  int r0 = blockIdx.y * 32, c0 = blockIdx.x * 32;
  int x = threadIdx.x, y = threadIdx.y;
  for (int i = y; i < 32; i += 8) t[i][x] = ip[(size_t)(r0 + i) * C + c0 + x];
  __syncthreads();
  for (int i = y; i < 32; i += 8) op[(size_t)(c0 + i) * R + r0 + x] = f2bf(t[x][i]);
}

// ------------- row softmax with mask, in-place f32 -> bf16 (row-local) -------------
// S: [rows][2048] f32.  P: same buffer reinterpreted, row stride 4096 u16, first 2048 used.
__global__ __launch_bounds__(256) void softmax_k(const float* __restrict__ S,
                                                 const int* __restrict__ mask,
                                                 u16* __restrict__ P, float scale) {
  __shared__ float redm[4], reds[4];
  const int row = blockIdx.x;
  const int bb = row >> 11;  // row / 2048
  const int tid = threadIdx.x;
  const float* s = S + (size_t)row * JMM;
  const int* mk = mask + (size_t)bb * JMM;
  float4 a = reinterpret_cast<const float4*>(s)[2 * tid];
  float4 c = reinterpret_cast<const float4*>(s)[2 * tid + 1];
  int4 ma = reinterpret_cast<const int4*>(mk)[2 * tid];
  int4 mc = reinterpret_cast<const int4*>(mk)[2 * tid + 1];
  float v[8];
  v[0] = ma.x ? a.x * scale : -1e30f;
  v[1] = ma.y ? a.y * scale : -1e30f;
  v[2] = ma.z ? a.z * scale : -1e30f;
  v[3] = ma.w ? a.w * scale : -1e30f;
  v[4] = mc.x ? c.x * scale : -1e30f;
  v[5] = mc.y ? c.y * scale : -1e30f;
  v[6] = mc.z ? c.z * scale : -1e30f;
  v[7] = mc.w ? c.w * scale : -1e30f;
  float mx = v[0];
  #pragma unroll
  for (int i = 1; i < 8; ++i) mx = fmaxf(mx, v[i]);
  for (int off = 32; off; off >>= 1) mx = fmaxf(mx, __shfl_xor(mx, off));
  if ((tid & 63) == 0) redm[tid >> 6] = mx;
  __syncthreads();
  mx = fmaxf(fmaxf(redm[0], redm[1]), fmaxf(redm[2], redm[3]));
  float sum = 0.f;
  #pragma unroll
  for (int i = 0; i < 8; ++i) { v[i] = __expf(v[i] - mx); sum += v[i]; }
  for (int off = 32; off; off >>= 1) sum += __shfl_xor(sum, off);
  if ((tid & 63) == 0) reds[tid >> 6] = sum;
  __syncthreads();
  sum = reds[0] + reds[1] + reds[2] + reds[3];
  float inv = 1.0f / sum;
  union { u16 u[8]; uint4 q; } r;
  #pragma unroll
  for (int i = 0; i < 8; ++i) r.u[i] = f2bf(v[i] * inv);
  reinterpret_cast<uint4*>(P + (size_t)row * 4096)[tid] = r.q;
}

// ------------- 128x128-tile bf16 MFMA GEMM, C = A @ Bt^T, templated epilogue -------------
// A: [M,K] bf16 row-major (lda), Bt: [N,K] bf16 row-major (ldb)
// EPI 0: relu -> bf16 Cb | 1: raw f32 Cf | 2: bf16 Cb | 3: gate (R0/R1 res, sigmoid, f32 Cf)
template <int EPI>
__global__ __launch_bounds__(256) void gemm_k(
    const u16* __restrict__ A, const u16* __restrict__ A2, const u16* __restrict__ Bt,
    float* __restrict__ Cf, u16* __restrict__ Cb,
    const float* __restrict__ R0, const u16* __restrict__ R1,
    int M, int N, int K, int lda, int ldb, int Ksplit,
    long long A_bs, long long B_bs, long long C_bs) {
  __shared__ u16 As[128 * 64];
  __shared__ u16 Bs[128 * 64];
  const int tid = threadIdx.x;
  const int wave = tid >> 6, lane = tid & 63;
  const size_t Aoff = (size_t)blockIdx.z * A_bs;
  const size_t Boff = (size_t)blockIdx.z * B_bs;
  const size_t Coff = (size_t)blockIdx.z * C_bs;
  const int m0 = blockIdx.y * 128, n0 = blockIdx.x * 128;
  const int wr = wave >> 1, wc = wave & 1;
  const int l15 = lane & 15, l4 = lane >> 4;
  const int arow = lane >> 3;        // 0..7 within an 8-row chunk
  const int acol = (lane & 7) * 8;   // bf16 element offset within row

  f32x4 acc[4][4];
  #pragma unroll
  for (int i = 0; i < 4; ++i)
    #pragma unroll
    for (int j = 0; j < 4; ++j) acc[i][j] = (f32x4){0.f, 0.f, 0.f, 0.f};

  for (int k0 = 0; k0 < K; k0 += 64) {
    const u16* Abase;
    int kloc;
    if (k0 < Ksplit) { Abase = A + Aoff; kloc = k0; }
    else             { Abase = A2 + Aoff; kloc = k0 - Ksplit; }
    __syncthreads();  // previous tile's reads done before overwrite
    #pragma unroll
    for (int c = 0; c < 4; ++c) {
      int chunk = wave * 4 + c;          // 0..15, 1KB each
      int row = chunk * 8 + arow;
      const u16* ga = Abase + (size_t)(m0 + row) * lda + kloc + acol;
      __builtin_amdgcn_global_load_lds(
          (const __attribute__((address_space(1))) void*)ga,
          (__attribute__((address_space(3))) void*)(&As[chunk * 512]), 16, 0, 0);
      const u16* gb = Bt + Boff + (size_t)(n0 + row) * ldb + k0 + acol;
      __builtin_amdgcn_global_load_lds(
          (const __attribute__((address_space(1))) void*)gb,
          (__attribute__((address_space(3))) void*)(&Bs[chunk * 512]), 16, 0, 0);
    }
    __syncthreads();  // drains vmcnt: tile resident
    #pragma unroll
    for (int kk = 0; kk < 64; kk += 32) {
      s16x8 af[4], bfr[4];
      #pragma unroll
      for (int mi = 0; mi < 4; ++mi)
        af[mi] = *reinterpret_cast<const s16x8*>(&As[(wr * 64 + mi * 16 + l15) * 64 + kk + l4 * 8]);
      #pragma unroll
      for (int ni = 0; ni < 4; ++ni)
        bfr[ni] = *reinterpret_cast<const s16x8*>(&Bs[(wc * 64 + ni * 16 + l15) * 64 + kk + l4 * 8]);
      #pragma unroll
      for (int mi = 0; mi < 4; ++mi)
        #pragma unroll
        for (int ni = 0; ni < 4; ++ni)
          acc[mi][ni] = mfma16(af[mi], bfr[ni], acc[mi][ni]);
    }
  }

  #pragma unroll
  for (int mi = 0; mi < 4; ++mi) {
    #pragma unroll
    for (int ni = 0; ni < 4; ++ni) {
      int col = n0 + wc * 64 + ni * 16 + l15;
      #pragma unroll
      for (int j = 0; j < 4; ++j) {
        int row = m0 + wr * 64 + mi * 16 + l4 * 4 + j;
        float v = acc[mi][ni][j];
        size_t cidx = Coff + (size_t)row * N + col;
        if (EPI == 0) {
          Cb[cidx] = f2bf(fmaxf(v, 0.f));
        } else if (EPI == 1) {
          Cf[cidx] = v;
        } else if (EPI == 2) {
          Cb[cidx] = f2bf(v);
        } else {
          float r = (col < Ksplit) ? R0[(size_t)row * 512 + col]
                                   : bf2f(R1[(size_t)row * 512 + (col - 512)]);
          float g = 1.0f / (1.0f + __expf(-v));
          Cf[cidx] = r * g;
        }
      }
    }
  }
}

extern "C" void kernel_launch(void* const* d_in, const int* in_sizes, int n_in,
                              void* d_out, int out_size, void* d_ws, size_t ws_size,
                              hipStream_t stream) {
  const float* inputs = (const float*)d_in[0];  // [8,2048,512]
  const float* memory = (const float*)d_in[1];  // [8,2048,512]
  const int*   mask   = (const int*)d_in[2];    // [8,2048]
  const float* Wq     = (const float*)d_in[3];  // [512,512]
  const float* Wk     = (const float*)d_in[4];  // [512,512]
  const float* Wg     = (const float*)d_in[5];  // [1024,1024]
  float* out = (float*)d_out;                   // [8,2048,1024]

  char* ws = (char*)d_ws;
  size_t off = 0;
  auto alloc = [&](size_t bytes) {
    void* p = ws + off;
    off += (bytes + 255) & ~(size_t)255;
    return p;
  };
  u16* in_b  = (u16*)alloc(16384ULL * 512 * 2);   // inputs bf16
  u16* mem_b = (u16*)alloc(16384ULL * 512 * 2);   // memory bf16
  u16* memT  = (u16*)alloc(16384ULL * 512 * 2);   // memory^T bf16 [B][D][JM]
  u16* WqT   = (u16*)alloc(512ULL * 512 * 2);
  u16* WkT   = (u16*)alloc(512ULL * 512 * 2);
  u16* WgT   = (u16*)alloc(1024ULL * 1024 * 2);
  u16* q_b   = (u16*)alloc(16384ULL * 512 * 2);
  u16* k_b   = (u16*)alloc(16384ULL * 512 * 2);
  float* sc  = (float*)alloc(8ULL * 2048 * 2048 * 4);  // scores f32, then P bf16 in-place
  u16* att_b = (u16*)alloc(16384ULL * 512 * 2);
  (void)ws_size; (void)in_sizes; (void)n_in; (void)out_size;

  const int n8 = (16384 * 512) / 8;  // 1048576
  cvt_k<<<(n8 + 255) / 256, 256, 0, stream>>>(inputs, in_b, n8);
  cvt_k<<<(n8 + 255) / 256, 256, 0, stream>>>(memory, mem_b, n8);
  dim3 tb(32, 8);
  tcvt_k<<<dim3(16, 16, 1), tb, 0, stream>>>(Wq, WqT, 512, 512, 0, 0);
  tcvt_k<<<dim3(16, 16, 1), tb, 0, stream>>>(Wk, WkT, 512, 512, 0, 0);
  tcvt_k<<<dim3(32, 32, 1), tb, 0, stream>>>(Wg, WgT, 1024, 1024, 0, 0);
  tcvt_k<<<dim3(16, 64, 8), tb, 0, stream>>>(memory, memT, 2048, 512,
                                             2048LL * 512, 2048LL * 512);

  // q = relu(inputs @ Wq), k = relu(memory @ Wk)   [16384, 512]
  gemm_k<0><<<dim3(4, 128, 1), 256, 0, stream>>>(in_b, nullptr, WqT, nullptr, q_b,
      nullptr, nullptr, 16384, 512, 512, 512, 512, 512, 0, 0, 0);
  gemm_k<0><<<dim3(4, 128, 1), 256, 0, stream>>>(mem_b, nullptr, WkT, nullptr, k_b,
      nullptr, nullptr, 16384, 512, 512, 512, 512, 512, 0, 0, 0);

  // scores[b] = q[b] @ k[b]^T   (raw, f32; scale+mask applied in softmax)
  gemm_k<1><<<dim3(16, 16, 8), 256, 0, stream>>>(q_b, nullptr, k_b, sc, nullptr,
      nullptr, nullptr, 2048, 2048, 512, 512, 512, 512,
      2048LL * 512, 2048LL * 512, 2048LL * 2048);

  // masked scaled softmax, bf16 P written in place (row stride 4096 u16)
  softmax_k<<<16384, 256, 0, stream>>>(sc, mask, (u16*)sc, 0.044194173824159216f);

  // att[b] = P[b] @ memory[b]   -> bf16
  gemm_k<2><<<dim3(4, 16, 8), 256, 0, stream>>>((const u16*)sc, nullptr, memT,
      nullptr, att_b, nullptr, nullptr, 2048, 512, 2048, 4096, 2048, 2048,
      2048LL * 4096, 512LL * 2048, 2048LL * 512);

  // out = res * sigmoid(res @ Wg), res = [inputs | att]   (ldb=1024 for WgT!)
  gemm_k<3><<<dim3(8, 128, 1), 256, 0, stream>>>(in_b, att_b, WgT, out, nullptr,
      inputs, att_b, 16384, 1024, 1024, 512, 1024, 512, 0, 0, 0);
}